// Round 3
// baseline (580.644 us; speedup 1.0000x reference)
//
#include <hip/hip_runtime.h>
#include <stdint.h>

// ---- problem constants ----
#define NTOK 32768
#define EMB  1024
#define QKVN 3072   // 3*EMB
#define NH   16
#define HD   64

typedef __bf16 bf16x8 __attribute__((ext_vector_type(8)));
typedef float  floatx4 __attribute__((ext_vector_type(4)));
typedef unsigned int   uintx4   __attribute__((ext_vector_type(4)));
typedef unsigned short ushortx4 __attribute__((ext_vector_type(4)));
typedef unsigned short ushortx8 __attribute__((ext_vector_type(8)));

__device__ __forceinline__ unsigned short f2bf_rne(float f){
    unsigned int x; __builtin_memcpy(&x, &f, 4);
    x += 0x7fffu + ((x >> 16) & 1u);
    return (unsigned short)(x >> 16);
}

__device__ __forceinline__ void async_copy16(void* lds, const void* gsrc){
    __builtin_amdgcn_global_load_lds(
        (const __attribute__((address_space(1))) unsigned int*)gsrc,
        (__attribute__((address_space(3))) unsigned int*)lds,
        16, 0, 0);
}

// ---------------- cast fp32 -> bf16, vectorized x4 ----------------
__global__ __launch_bounds__(256) void cast_f32_bf16(const float* __restrict__ in,
                                                     unsigned short* __restrict__ out,
                                                     int n4){
    int idx = blockIdx.x * 256 + threadIdx.x;
    if (idx < n4){
        floatx4 v = ((const floatx4*)in)[idx];
        ushortx4 o;
        o[0] = f2bf_rne(v[0]); o[1] = f2bf_rne(v[1]);
        o[2] = f2bf_rne(v[2]); o[3] = f2bf_rne(v[3]);
        ((ushortx4*)out)[idx] = o;
    }
}

// =======================================================================
// QKV GEMM, 256x256 tile, BK=64, 8 waves, 8-phase read-ahead (frozen after
// r1/r2 null results). NOW SPLIT into 2 dispatches of N=1536 (768 blocks)
// so attn_mfma surfaces in the rocprof top-5 for diagnosis.
// The V third of C (cols >= 2048) is written TRANSPOSED within each token:
// logical (head j, dim d) -> physical col 2048 + d*16 + j, so attn can stage
// V^T with vectorized b128 writes instead of a scalar scatter.
// =======================================================================

__device__ __forceinline__ void stage_a_q(unsigned short* At, const unsigned short* A,
                                          int m0, int q, int kt, int tid){
    int g     = tid >> 8;
    int rl    = (tid & 255) >> 3;
    int chunk = tid & 7;
    int row   = g * 128 + q * 32 + rl;
    int k8    = chunk ^ (row & 7);
    async_copy16((char*)At + row * 128 + chunk * 16,
                 &A[(size_t)(m0 + row) * EMB + kt + k8 * 8]);
}

__device__ __forceinline__ void stage_b_half(unsigned short* Bt, const unsigned short* B,
                                             int n0, int h, int kt, int tid){
    #pragma unroll
    for (int j = 0; j < 2; j++){
        int qg    = j * 2 + (tid >> 8);
        int row0  = qg * 64 + h * 32;
        int t2    = tid & 255;
        int rl    = t2 >> 3;
        int chunk = tid & 7;
        int row   = row0 + rl;
        int k8    = chunk ^ (row & 7);
        async_copy16((char*)Bt + row0 * 128 + t2 * 16,
                     &B[(size_t)(n0 + row) * EMB + kt + k8 * 8]);
    }
}

#define LDA_Q(DST, BUF, Q)                                                          \
    _Pragma("unroll")                                                               \
    for (int mi = 0; mi < 2; mi++){                                                 \
        int row = wm * 128 + (Q) * 32 + mi * 16 + r16;                              \
        _Pragma("unroll")                                                           \
        for (int ks = 0; ks < 2; ks++)                                              \
            DST[mi][ks] = *(const bf16x8*)&(BUF)[row * 64 + (((quad + 4*ks) ^ (row & 7)) * 8)]; \
    }

#define LDB_P(DST, BUF, P)                                                          \
    _Pragma("unroll")                                                               \
    for (int ni = 0; ni < 2; ni++){                                                 \
        int row = wn * 64 + (P) * 32 + ni * 16 + r16;                               \
        _Pragma("unroll")                                                           \
        for (int ks = 0; ks < 2; ks++)                                              \
            DST[ni][ks] = *(const bf16x8*)&(BUF)[row * 64 + (((quad + 4*ks) ^ (row & 7)) * 8)]; \
    }

#define MFMA8(Q, P, AS, BS)                                                         \
    _Pragma("unroll")                                                               \
    for (int mi = 0; mi < 2; mi++)                                                  \
        _Pragma("unroll")                                                           \
        for (int ni = 0; ni < 2; ni++)                                              \
            _Pragma("unroll")                                                       \
            for (int ks = 0; ks < 2; ks++)                                          \
                acc[(Q)*2 + mi][(P)*2 + ni] = __builtin_amdgcn_mfma_f32_16x16x32_bf16( \
                    AS[mi][ks], BS[ni][ks], acc[(Q)*2 + mi][(P)*2 + ni], 0, 0, 0);

#define SETP1 __builtin_amdgcn_s_setprio(1)
#define SETP0 __builtin_amdgcn_s_setprio(0)
#define BAR   __builtin_amdgcn_s_barrier()

__device__ __forceinline__ void ktile8(const unsigned short* __restrict__ A,
                                       const unsigned short* __restrict__ B,
                                       unsigned short* curA, unsigned short* curB,
                                       unsigned short* nxtA, unsigned short* nxtB,
                                       int m0, int n0, int kt, int tid,
                                       bf16x8 (&aX)[2][2], bf16x8 (&aY)[2][2],
                                       bf16x8 (&b01)[2][2], bf16x8 (&b23)[2][2],
                                       floatx4 (&acc)[8][4]){
    const int lane = tid & 63;
    const int wave = tid >> 6;
    const int wm = wave >> 2, wn = wave & 3;
    const int r16 = lane & 15, quad = lane >> 4;
    const int ks2 = kt + 128;   // staging K-base (tile t+2)

    SETP1; MFMA8(0, 0, aX, b01); SETP0; BAR;

    LDA_Q(aY, curA, 1);
    stage_a_q(curA, A, m0, 0, ks2, tid);
    stage_b_half(curB, B, n0, 0, ks2, tid);
    SETP1; MFMA8(0, 1, aX, b23); SETP0; BAR;

    stage_b_half(curB, B, n0, 1, ks2, tid);
    SETP1; MFMA8(1, 1, aY, b23); SETP0; BAR;

    LDA_Q(aX, curA, 2);
    stage_a_q(curA, A, m0, 1, ks2, tid);
    SETP1; MFMA8(1, 0, aY, b01); SETP0; BAR;

    SETP1; MFMA8(2, 0, aX, b01); SETP0; BAR;

    LDA_Q(aY, curA, 3);
    stage_a_q(curA, A, m0, 2, ks2, tid);
    SETP1; MFMA8(2, 1, aX, b23); SETP0; BAR;

    SETP1; MFMA8(3, 1, aY, b23); SETP0;
    asm volatile("s_waitcnt vmcnt(7)" ::: "memory");
    BAR;

    LDB_P(b23, nxtB, 1);
    LDA_Q(aX, nxtA, 0);
    SETP1; MFMA8(3, 0, aY, b01); SETP0;
    LDB_P(b01, nxtB, 0);
    stage_a_q(curA, A, m0, 3, ks2, tid);
    BAR;
}

__global__ __launch_bounds__(512, 2) void qkv_gemm256(const unsigned short* __restrict__ A,
                                                      const unsigned short* __restrict__ B,
                                                      const float* __restrict__ bias,
                                                      unsigned short* __restrict__ C,
                                                      int n_off){
    extern __shared__ __align__(16) unsigned short lds[];
    unsigned short* A0 = lds;             // 32 KB each
    unsigned short* B0 = lds + 16384;
    unsigned short* A1 = lds + 32768;
    unsigned short* B1 = lds + 49152;

    const int tid = threadIdx.x;
    // XCD-aware swizzle: nwg = 768, 768 % 8 == 0 -> bijective.
    int bid = blockIdx.x;
    int swz = (bid & 7) * 96 + (bid >> 3);
    int by  = swz / 6;
    int bx  = swz - by * 6;
    const int m0 = by * 256, n0 = n_off + bx * 256;

    const int lane = tid & 63;
    const int wave = tid >> 6;
    const int wm = wave >> 2, wn = wave & 3;
    const int r16 = lane & 15, quad = lane >> 4;

    floatx4 acc[8][4];
    #pragma unroll
    for (int i = 0; i < 8; i++)
        #pragma unroll
        for (int j = 0; j < 4; j++) acc[i][j] = floatx4{0.f, 0.f, 0.f, 0.f};

    // ---- prologue: stage T0 then T1 ----
    #pragma unroll
    for (int q = 0; q < 4; q++) stage_a_q(A0, A, m0, q, 0, tid);
    stage_b_half(B0, B, n0, 0, 0, tid);
    stage_b_half(B0, B, n0, 1, 0, tid);
    #pragma unroll
    for (int q = 0; q < 4; q++) stage_a_q(A1, A, m0, q, 64, tid);
    stage_b_half(B1, B, n0, 0, 64, tid);
    stage_b_half(B1, B, n0, 1, 64, tid);
    asm volatile("s_waitcnt vmcnt(8)" ::: "memory");
    BAR;

    bf16x8 aX[2][2], aY[2][2], b01[2][2], b23[2][2];
    LDA_Q(aX, A0, 0);
    LDB_P(b01, B0, 0);
    LDB_P(b23, B0, 1);

    #pragma unroll 1
    for (int t = 0; t < 16; t += 2){
        ktile8(A, B, A0, B0, A1, B1, m0, n0, t * 64,      tid, aX, aY, b01, b23, acc);
        ktile8(A, B, A1, B1, A0, B0, m0, n0, t * 64 + 64, tid, aX, aY, b01, b23, acc);
    }

    // ---- epilogue: C/D layout col = lane&15, row = quad*4 + r (verified) ----
    // V third (cols >= 2048): store transposed within token: (j,d) -> 2048+d*16+j
    #pragma unroll
    for (int ni = 0; ni < 4; ni++){
        int gcol = n0 + wn * 64 + ni * 16 + r16;
        float bv = bias[gcol];
        int pcol = gcol;
        if (gcol >= 2048){
            int off = gcol - 2048;
            pcol = 2048 + ((off & 63) << 4) + (off >> 6);
        }
        #pragma unroll
        for (int mi = 0; mi < 8; mi++){
            #pragma unroll
            for (int r = 0; r < 4; r++){
                int grow = m0 + wm * 128 + mi * 16 + quad * 4 + r;
                C[(size_t)grow * QKVN + pcol] = f2bf_rne(acc[mi][ni][r] + bv);
            }
        }
    }
}

// ---------------- MFMA per-token cross-head attention ----------------
// Grid-stride: 2048 blocks x 4 token-groups (4 tokens/group, 1 wave/token).
// T14 async-STAGE: global->reg loads for group g+1 issued at compute(g) start
// (HBM latency hides under compute); reg->LDS write after end-of-iter barrier.
// V third of qkv is PRE-TRANSPOSED by the GEMM epilogue, so V^T staging is
// vectorized b128 writes (same LDS layout as the verified scatter version).
// LDS per token (shorts): k[16][72] @0, vT[64][24] @1152, p[16][24] @2688.
#define TOKL 3072
#define KOFF 0
#define VOFF 1152
#define POFF 2688

__device__ __forceinline__ void attn_issue(const unsigned short* __restrict__ qkv,
                                           int g, int tid, int wave, int col, int quad,
                                           ushortx8 (&kk)[2], ushortx8 (&vv)[2],
                                           bf16x8& qf0, bf16x8& qf1){
    #pragma unroll
    for (int s = 0; s < 2; s++){
        int c = tid + s * 256, t = c >> 7, rem = c & 127;
        const unsigned short* base = qkv + (size_t)(g * 4 + t) * QKVN;
        kk[s] = *(const ushortx8*)(base + EMB   + (rem >> 3) * HD + (rem & 7) * 8);
        vv[s] = *(const ushortx8*)(base + 2*EMB + (rem >> 1) * 16 + (rem & 1) * 8);
    }
    const unsigned short* qrow = qkv + (size_t)(g * 4 + wave) * QKVN + col * HD;
    qf0 = *(const bf16x8*)(qrow + quad * 8);
    qf1 = *(const bf16x8*)(qrow + 32 + quad * 8);
}

__global__ __launch_bounds__(256, 5) void attn_mfma(const unsigned short* __restrict__ qkv,
                                                    float* __restrict__ out){
    __shared__ unsigned short sm[4 * TOKL];   // 24 KB

    const int tid  = threadIdx.x;
    const int wave = tid >> 6;
    const int lane = tid & 63;
    const int col  = lane & 15;
    const int quad = lane >> 4;

    const int g0 = blockIdx.x * 4;
    ushortx8 kk[2], vv[2];
    bf16x8 qf0, qf1;
    attn_issue(qkv, g0, tid, wave, col, quad, kk, vv, qf0, qf1);

    #pragma unroll 1
    for (int it = 0; it < 4; it++){
        const int g = g0 + it;

        // ---- write staged K / V^T (vectorized, conflict-light) ----
        #pragma unroll
        for (int s = 0; s < 2; s++){
            int c = tid + s * 256, t = c >> 7, rem = c & 127;
            *(ushortx8*)&sm[t * TOKL + KOFF + (rem >> 3) * 72 + (rem & 7) * 8] = kk[s];
            *(ushortx8*)&sm[t * TOKL + VOFF + (rem >> 1) * 24 + (rem & 1) * 8] = vv[s];
        }
        __syncthreads();

        // keep this group's Q; prefetch next group's K/V/Q into regs (T14)
        bf16x8 q0 = qf0, q1 = qf1;
        int gn = (it < 3) ? g + 1 : g;      // clamped re-read on last iter (harmless)
        attn_issue(qkv, gn, tid, wave, col, quad, kk, vv, qf0, qf1);

        const int n = g * 4 + wave;
        unsigned short* tb = &sm[wave * TOKL];

        // ---- S = Q·K^T ----
        bf16x8 kf0 = *(const bf16x8*)&tb[KOFF + col * 72 + quad * 8];
        bf16x8 kf1 = *(const bf16x8*)&tb[KOFF + col * 72 + 32 + quad * 8];
        floatx4 sAcc = floatx4{0.f, 0.f, 0.f, 0.f};
        sAcc = __builtin_amdgcn_mfma_f32_16x16x32_bf16(q0, kf0, sAcc, 0, 0, 0);
        sAcc = __builtin_amdgcn_mfma_f32_16x16x32_bf16(q1, kf1, sAcc, 0, 0, 0);

        // ---- softmax over j (16 lanes of quad-group hold j=0..15) ----
        #pragma unroll
        for (int r = 0; r < 4; r++){
            float sv = sAcc[r] * 0.03125f;
            float m = sv;
            m = fmaxf(m, __shfl_xor(m, 1));
            m = fmaxf(m, __shfl_xor(m, 2));
            m = fmaxf(m, __shfl_xor(m, 4));
            m = fmaxf(m, __shfl_xor(m, 8));
            float p = __expf(sv - m);
            float l = p;
            l += __shfl_xor(l, 1);
            l += __shfl_xor(l, 2);
            l += __shfl_xor(l, 4);
            l += __shfl_xor(l, 8);
            p *= 1.f / l;
            tb[POFF + (quad * 4 + r) * 24 + col] = f2bf_rne(p);
        }
        // wave-private LDS region: program-order ds_write -> ds_read

        // ---- P A-frag (K padded to 32; quads 2,3 supply zeros) ----
        bf16x8 pf;
        #pragma unroll
        for (int z = 0; z < 8; z++) pf[z] = (__bf16)0.0f;
        if (quad < 2) pf = *(const bf16x8*)&tb[POFF + col * 24 + quad * 8];

        // ---- O = P·V, 4 d-blocks of 16 ----
        #pragma unroll
        for (int dblk = 0; dblk < 4; dblk++){
            bf16x8 vf;
            #pragma unroll
            for (int z = 0; z < 8; z++) vf[z] = (__bf16)0.0f;
            if (quad < 2) vf = *(const bf16x8*)&tb[VOFF + (dblk * 16 + col) * 24 + quad * 8];
            floatx4 o = __builtin_amdgcn_mfma_f32_16x16x32_bf16(
                            pf, vf, floatx4{0.f, 0.f, 0.f, 0.f}, 0, 0, 0);
            #pragma unroll
            for (int r = 0; r < 4; r++){
                int i = quad * 4 + r;
                out[(size_t)i * (NTOK * HD) + (size_t)n * HD + dblk * 16 + col] = o[r];
            }
        }
        __syncthreads();   // protect LDS before next iter's staging writes
    }
}

extern "C" void kernel_launch(void* const* d_in, const int* in_sizes, int n_in,
                              void* d_out, int out_size, void* d_ws, size_t ws_size,
                              hipStream_t stream){
    const float* h = (const float*)d_in[0];   // [32768][1024]
    const float* W = (const float*)d_in[1];   // [3072][1024]
    const float* b = (const float*)d_in[2];   // [3072]
    float* out = (float*)d_out;               // 33554432 fp32

    char* ws = (char*)d_ws;
    unsigned short* h_bf = (unsigned short*)ws;                              // 64 MB
    unsigned short* w_bf = (unsigned short*)(ws + (size_t)64 * 1024 * 1024); // 6 MB
    unsigned short* qkv  = (unsigned short*)(ws + (size_t)72 * 1024 * 1024); // 192 MB bf16

    static bool attr_set = false;
    if (!attr_set){
        hipFuncSetAttribute(reinterpret_cast<const void*>(qkv_gemm256),
                            hipFuncAttributeMaxDynamicSharedMemorySize, 131072);
        attr_set = true;
    }

    cast_f32_bf16<<<(NTOK * EMB / 4 + 255) / 256, 256, 0, stream>>>(h, h_bf, NTOK * EMB / 4);
    cast_f32_bf16<<<(QKVN * EMB / 4 + 255) / 256, 256, 0, stream>>>(W, w_bf, QKVN * EMB / 4);

    // split into two N=1536 dispatches so attn_mfma surfaces in rocprof top-5
    qkv_gemm256<<<dim3(768), 512, 131072, stream>>>(h_bf, w_bf, b, qkv, 0);
    qkv_gemm256<<<dim3(768), 512, 131072, stream>>>(h_bf, w_bf, b, qkv, 1536);

    attn_mfma<<<NTOK / 16, 256, 0, stream>>>(qkv, out);
}